// Round 2
// baseline (26.360 us; speedup 1.0000x reference)
//
#include <hip/hip_runtime.h>

#define NN 1024
#define DD 128

typedef float f32x4 __attribute__((ext_vector_type(4)));
typedef float f32x16 __attribute__((ext_vector_type(16)));
typedef _Float16 f16x8 __attribute__((ext_vector_type(8)));

union H2 { unsigned u; _Float16 h[2]; };

__device__ __forceinline__ f16x8 cvt8(f32x4 a, f32x4 b) {
  f16x8 r;
  r[0] = (_Float16)a.x; r[1] = (_Float16)a.y; r[2] = (_Float16)a.z; r[3] = (_Float16)a.w;
  r[4] = (_Float16)b.x; r[5] = (_Float16)b.y; r[6] = (_Float16)b.z; r[7] = (_Float16)b.w;
  return r;
}

// Pre-kernel, 528 blocks:
//  bid<512: zero dK (131072 f32) + row norms xx->ws[0..1024), yy->ws[1024..2048)
//  bid>=512 (16 blocks): build Ytb = f16 Y^T [128][1024] at ws+2048 via LDS transpose
__global__ void pre_k(const float* __restrict__ X, const float* __restrict__ Y,
                      float* __restrict__ ws, float* __restrict__ dk) {
  __shared__ _Float16 T[128][72];   // 64-j tile, padded row (144B = 36 banks)
  const int bid = blockIdx.x, tid = threadIdx.x;
  if (bid < 512) {
    int ft = bid * 256 + tid;                 // 0..131071
    dk[ft] = 0.0f;
    int wid = ft >> 6;                        // 0..2047
    int ln  = ft & 63;
    const float* src = (wid < NN) ? X : Y;
    int row = wid & (NN - 1);
    float a = src[row * DD + ln];
    float b = src[row * DD + 64 + ln];
    float v = a * a + b * b;
    #pragma unroll
    for (int off = 32; off; off >>= 1) v += __shfl_xor(v, off);
    if (ln == 0) ws[wid] = v;
  } else {
    int jb = bid - 512;                       // 0..15, 64 j-rows each
    #pragma unroll
    for (int p = 0; p < 8; ++p) {
      int idx = tid + 256 * p;                // 0..2047
      int j = idx >> 5, d4 = idx & 31;
      f32x4 v = *(const f32x4*)(Y + (jb * 64 + j) * DD + 4 * d4);
      T[4 * d4 + 0][j] = (_Float16)v.x;
      T[4 * d4 + 1][j] = (_Float16)v.y;
      T[4 * d4 + 2][j] = (_Float16)v.z;
      T[4 * d4 + 3][j] = (_Float16)v.w;
    }
    __syncthreads();
    _Float16* Ytb = (_Float16*)(ws + 2048);
    int d = tid >> 1, h = tid & 1;
    #pragma unroll
    for (int s = 0; s < 4; ++s) {
      f16x8 vv = *(const f16x8*)&T[d][32 * h + 8 * s];
      *(f16x8*)(Ytb + d * NN + jb * 64 + 32 * h + 8 * s) = vv;
    }
  }
}

// Main: grid (8 js, 32 ib), 4 waves. No operand LDS staging:
// QK^T fragments built on the fly from global f32 X/Y; K@Y B-operand from
// pre-transposed f16 Ytb in ws. Only K' (8KB, swizzled) + reductions in LDS.
__global__ __launch_bounds__(256) void gk_main(const float* __restrict__ X,
                                               const float* __restrict__ Y,
                                               const int* __restrict__ hp,
                                               const float* __restrict__ ws,
                                               float* __restrict__ out) {
  __shared__ __align__(16) _Float16 Ks[32 * 128];  // K' f16-scaled, chunk-XOR swizzled
  __shared__ float yys[128];
  __shared__ unsigned msc[32];
  __shared__ float Sred[32];

  const int tid = threadIdx.x;
  const int js  = blockIdx.x;       // 0..7
  const int ib  = blockIdx.y;       // 0..31
  const int lane = tid & 63;
  const int w   = tid >> 6;         // wave 0..3
  const int t   = lane >> 5;        // half-wave
  const int li  = lane & 31;

  const float fh = (float)hp[0];
  const float inv_h2 = 1.0f / (fh * fh);
  const _Float16* Ytb = (const _Float16*)(ws + 2048);

  if (tid < 32) { msc[tid] = 0u; Sred[tid] = 0.0f; }
  if (tid < 128) yys[tid] = ws[NN + js * 128 + tid];
  __syncthreads();

  // ---- QK^T: A = Y rows (m=j), B = X rows (n=i), frags from global f32 ----
  f32x16 acc = {};
  const int jr = js * 128 + w * 32 + li;
  const int xrow = ib * 32 + li;
  #pragma unroll
  for (int kt = 0; kt < 8; ++kt) {
    int d0 = (2 * kt + t) * 8;
    f32x4 ya = *(const f32x4*)(Y + jr * DD + d0);
    f32x4 yb = *(const f32x4*)(Y + jr * DD + d0 + 4);
    f32x4 xa = *(const f32x4*)(X + xrow * DD + d0);
    f32x4 xb = *(const f32x4*)(X + xrow * DD + d0 + 4);
    acc = __builtin_amdgcn_mfma_f32_32x32x16_f16(cvt8(ya, yb), cvt8(xa, xb), acc, 0, 0, 0);
  }

  // ---- exp: K = exp(inv_h2*(xy - 0.5*(xx+yy))), clamped <= 1 ----
  const float xxv = ws[ib * 32 + li];
  float K[16];
  float m = 0.0f, sp = 0.0f;
  #pragma unroll
  for (int r = 0; r < 16; ++r) {
    int jl = (r & 3) + 8 * (r >> 2) + 4 * t;
    float yyv = yys[w * 32 + jl];
    float e = fminf((acc[r] - 0.5f * (xxv + yyv)) * inv_h2, 0.0f);
    float kv = exp2f(e * 1.44269504088896341f);
    K[r] = kv; m = fmaxf(m, kv); sp += kv;
  }
  // K store: lane = row i, reg quads are 4 consecutive j
  {
    float* kb = out + (ib * 32 + li) * NN + js * 128 + w * 32 + 4 * t;
    #pragma unroll
    for (int s = 0; s < 4; ++s) {
      f32x4 kv = { K[4 * s], K[4 * s + 1], K[4 * s + 2], K[4 * s + 3] };
      *(f32x4*)(kb + 8 * s) = kv;
    }
  }

  m = fmaxf(m, __shfl_xor(m, 32));
  if (t == 0) atomicMax(&msc[li], __float_as_uint(m));
  atomicAdd(&Sred[li], sp);
  __syncthreads();

  {
    unsigned ue = (msc[li] >> 23) & 0xffu;
    unsigned se = 266u - ue; if (se > 254u) se = 254u;   // K'max in [2^12, 2^13)
    float scale = __uint_as_float(se << 23);
    #pragma unroll
    for (int c = 0; c < 8; ++c) {
      H2 pk;
      pk.h[0] = (_Float16)(K[2 * c] * scale);
      pk.h[1] = (_Float16)(K[2 * c + 1] * scale);
      int g = (4 * w + (c >> 1)) ^ (li & 7);
      *(unsigned*)((char*)Ks + li * 256 + g * 16 + t * 8 + (c & 1) * 4) = pk.u;
    }
  }
  __syncthreads();

  // ---- K'@Y: A = Ks rows (m=i), B = Ytb rows (n=d) straight from ws ----
  f32x16 acc2 = {};
  const int drow = w * 32 + li;
  #pragma unroll
  for (int jt = 0; jt < 8; ++jt) {
    int ga = (2 * jt + t) ^ (li & 7);
    f16x8 af = *(const f16x8*)((const char*)Ks + li * 256 + ga * 16);
    f16x8 bf = *(const f16x8*)(Ytb + drow * NN + js * 128 + (2 * jt + t) * 8);
    acc2 = __builtin_amdgcn_mfma_f32_32x32x16_f16(af, bf, acc2, 0, 0, 0);
  }
  float* dkp = out + NN * NN;
  #pragma unroll
  for (int r = 0; r < 16; ++r) {
    int il = (r & 3) + 8 * (r >> 2) + 4 * t;
    unsigned ue = (msc[il] >> 23) & 0xffu;
    unsigned se = 266u - ue; if (se > 254u) se = 254u;
    float invs = __uint_as_float((254u - se) << 23);
    float sred = Sred[il];
    int gi = ib * 32 + il;
    float xv = X[gi * DD + drow];
    float val = (acc2[r] * invs - sred * xv) * inv_h2;
    atomicAdd(dkp + gi * DD + drow, val);
  }
}

extern "C" void kernel_launch(void* const* d_in, const int* in_sizes, int n_in,
                              void* d_out, int out_size, void* d_ws, size_t ws_size,
                              hipStream_t stream) {
  const float* X = (const float*)d_in[0];
  const float* Y = (const float*)d_in[1];
  const int*   hp = (const int*)d_in[2];
  float* out = (float*)d_out;
  float* ws  = (float*)d_ws;     // 8 KB norms + 256 KB f16 Y^T = 264 KB

  hipLaunchKernelGGL(pre_k, dim3(528), dim3(256), 0, stream,
                     X, Y, ws, out + (size_t)NN * NN);
  hipLaunchKernelGGL(gk_main, dim3(8, 32), dim3(256), 0, stream,
                     X, Y, hp, ws, out);
}

// Round 3
// 20.710 us; speedup vs baseline: 1.2728x; 1.2728x over previous
//
#include <hip/hip_runtime.h>

#define NN 1024
#define DD 128

typedef float f32x4 __attribute__((ext_vector_type(4)));
typedef _Float16 f16x8 __attribute__((ext_vector_type(8)));

__device__ __forceinline__ f16x8 cvt8(f32x4 a, f32x4 b) {
  f16x8 r;
  r[0] = (_Float16)a.x; r[1] = (_Float16)a.y; r[2] = (_Float16)a.z; r[3] = (_Float16)a.w;
  r[4] = (_Float16)b.x; r[5] = (_Float16)b.y; r[6] = (_Float16)b.z; r[7] = (_Float16)b.w;
  return r;
}

// Single fused kernel. Grid (8 js, 64 ib), 256 threads = 4 waves.
// Block tile: 16 i x 128 j. Wave w owns j-subtile [w*32, w*32+32) as two
// 16x16x32 MFMA tiles (QK^T, swapped: lane=col=i, regs=row=j), then d-subtile
// [w*32, w*32+32) for the K'@Y GEMM (contraction over the block's 128 j).
__global__ __launch_bounds__(256) void gk_fused(const float* __restrict__ X,
                                                const float* __restrict__ Y,
                                                const int* __restrict__ hp,
                                                float* __restrict__ out) {
  __shared__ __align__(16) float    Kt[16][132];   // K f32 (for coalesced store)
  __shared__ __align__(16) _Float16 Ks[16][136];   // K' f16 scaled (phase-D A-frags)
  __shared__ float yys[128];
  __shared__ unsigned msc[16];
  __shared__ float Sred[16];

  const int tid  = threadIdx.x;
  const int js   = blockIdx.x;          // 0..7   (j block of 128)
  const int ib   = blockIdx.y;          // 0..63  (i block of 16)
  const int lane = tid & 63;
  const int w    = tid >> 6;            // wave 0..3
  const int g    = lane >> 4;           // k-group 0..3
  const int li   = lane & 15;

  const float fh = (float)hp[0];
  const float inv_h2 = 1.0f / (fh * fh);

  if (tid < 16) { msc[tid] = 0u; Sred[tid] = 0.0f; }

  // ---- Phase A: QK^T fragments straight from global f32; norms in-register ----
  const float* Xr = X + (size_t)(ib * 16 + li) * DD;
  f32x4 xa[4][2];
  float xx = 0.f;
  #pragma unroll
  for (int kt = 0; kt < 4; ++kt) {
    int d0 = kt * 32 + g * 8;
    xa[kt][0] = *(const f32x4*)(Xr + d0);
    xa[kt][1] = *(const f32x4*)(Xr + d0 + 4);
    #pragma unroll
    for (int c = 0; c < 4; ++c)
      xx += xa[kt][0][c] * xa[kt][0][c] + xa[kt][1][c] * xa[kt][1][c];
  }
  xx += __shfl_xor(xx, 16); xx += __shfl_xor(xx, 32);   // sum the 4 k-groups

  const float* Yr0 = Y + (size_t)(js * 128 + w * 32 + li) * DD;
  const float* Yr1 = Yr0 + 16 * DD;
  f32x4 acc0 = {0.f, 0.f, 0.f, 0.f}, acc1 = {0.f, 0.f, 0.f, 0.f};
  float yy0 = 0.f, yy1 = 0.f;
  #pragma unroll
  for (int kt = 0; kt < 4; ++kt) {
    int d0 = kt * 32 + g * 8;
    f32x4 a0 = *(const f32x4*)(Yr0 + d0), b0 = *(const f32x4*)(Yr0 + d0 + 4);
    f32x4 a1 = *(const f32x4*)(Yr1 + d0), b1 = *(const f32x4*)(Yr1 + d0 + 4);
    #pragma unroll
    for (int c = 0; c < 4; ++c) {
      yy0 += a0[c] * a0[c] + b0[c] * b0[c];
      yy1 += a1[c] * a1[c] + b1[c] * b1[c];
    }
    f16x8 bf = cvt8(xa[kt][0], xa[kt][1]);
    acc0 = __builtin_amdgcn_mfma_f32_16x16x32_f16(cvt8(a0, b0), bf, acc0, 0, 0, 0);
    acc1 = __builtin_amdgcn_mfma_f32_16x16x32_f16(cvt8(a1, b1), bf, acc1, 0, 0, 0);
  }
  yy0 += __shfl_xor(yy0, 16); yy0 += __shfl_xor(yy0, 32);
  yy1 += __shfl_xor(yy1, 16); yy1 += __shfl_xor(yy1, 32);
  if (lane < 16) { yys[w * 32 + lane] = yy0; yys[w * 32 + 16 + lane] = yy1; }
  __syncthreads();   // b1: yys ready, msc/Sred init visible

  // ---- exp: K = exp(inv_h2*(xy - 0.5(xx+yy))) clamped <= 1; stats in-reg ----
  float K[8];
  float m = 0.f, sp = 0.f;
  #pragma unroll
  for (int t = 0; t < 2; ++t) {
    f32x4 a = t ? acc1 : acc0;
    #pragma unroll
    for (int r = 0; r < 4; ++r) {
      int jl = w * 32 + t * 16 + 4 * g + r;            // C/D row map (16x16)
      float e = fminf((a[r] - 0.5f * (xx + yys[jl])) * inv_h2, 0.0f);
      float kv = exp2f(e * 1.44269504088896341f);
      K[t * 4 + r] = kv; m = fmaxf(m, kv); sp += kv;
      Kt[li][jl] = kv;
    }
  }
  m = fmaxf(m, __shfl_xor(m, 16)); m = fmaxf(m, __shfl_xor(m, 32));
  sp += __shfl_xor(sp, 16);        sp += __shfl_xor(sp, 32);
  if (lane < 16) {
    atomicMax(&msc[li], __float_as_uint(m));
    atomicAdd(&Sred[li], sp);
  }
  __syncthreads();   // b2: Kt, msc, Sred complete

  // ---- coalesced K store (full-line writes, 512B runs per row) ----
  {
    int i = tid >> 4, seg = tid & 15;
    f32x4 v0 = *(const f32x4*)&Kt[i][seg * 8];
    f32x4 v1 = *(const f32x4*)&Kt[i][seg * 8 + 4];
    float* kb = out + (size_t)(ib * 16 + i) * NN + js * 128 + seg * 8;
    *(f32x4*)kb = v0; *(f32x4*)(kb + 4) = v1;
  }
  // ---- scaled K' (f16) for phase D ----
  {
    unsigned ue = (msc[li] >> 23) & 0xffu;
    unsigned se = 266u - ue; if (se > 254u) se = 254u;  // K'max in [2^12,2^13)
    float scale = __uint_as_float(se << 23);
    #pragma unroll
    for (int t = 0; t < 2; ++t)
      #pragma unroll
      for (int r = 0; r < 4; ++r)
        Ks[li][w * 32 + t * 16 + 4 * g + r] = (_Float16)(K[t * 4 + r] * scale);
  }
  __syncthreads();   // b3: Ks ready

  // ---- Phase D: dK partial = K' @ Y  (A from LDS, B = Y columns from global) ----
  f32x4 c0 = {0.f, 0.f, 0.f, 0.f}, c1 = {0.f, 0.f, 0.f, 0.f};
  const int dA = w * 32 + li;       // d for sub-tile 0
  const int dB = dA + 16;           // d for sub-tile 1
  #pragma unroll
  for (int kt = 0; kt < 4; ++kt) {
    f16x8 af = *(const f16x8*)&Ks[li][kt * 32 + g * 8];
    const float* Yb = Y + (size_t)(js * 128 + kt * 32 + g * 8) * DD;
    f16x8 b0, b1;
    #pragma unroll
    for (int e = 0; e < 8; ++e) {
      b0[e] = (_Float16)Yb[e * DD + dA];   // lane=d: 64B-coalesced per k-group
      b1[e] = (_Float16)Yb[e * DD + dB];
    }
    c0 = __builtin_amdgcn_mfma_f32_16x16x32_f16(af, b0, c0, 0, 0, 0);
    c1 = __builtin_amdgcn_mfma_f32_16x16x32_f16(af, b1, c1, 0, 0, 0);
  }

  // ---- epilogue: unscale, subtract S_i * X, accumulate into dK ----
  float* dkp = out + (size_t)NN * NN;
  #pragma unroll
  for (int r = 0; r < 4; ++r) {
    int il = 4 * g + r;
    unsigned ue2 = (msc[il] >> 23) & 0xffu;
    unsigned se2 = 266u - ue2; if (se2 > 254u) se2 = 254u;
    float invs = __uint_as_float((254u - se2) << 23);   // 1/scale for row il
    float sred = Sred[il];
    int gi = ib * 16 + il;
    float x0 = X[(size_t)gi * DD + dA];
    float x1 = X[(size_t)gi * DD + dB];
    atomicAdd(dkp + (size_t)gi * DD + dA, (c0[r] * invs - sred * x0) * inv_h2);
    atomicAdd(dkp + (size_t)gi * DD + dB, (c1[r] * invs - sred * x1) * inv_h2);
  }
}

extern "C" void kernel_launch(void* const* d_in, const int* in_sizes, int n_in,
                              void* d_out, int out_size, void* d_ws, size_t ws_size,
                              hipStream_t stream) {
  const float* X  = (const float*)d_in[0];
  const float* Y  = (const float*)d_in[1];
  const int*   hp = (const int*)d_in[2];
  float* out = (float*)d_out;

  // zero the d_K_sum region (async fill is graph-capturable)
  hipMemsetAsync((void*)(out + (size_t)NN * NN), 0, (size_t)NN * DD * sizeof(float), stream);
  hipLaunchKernelGGL(gk_fused, dim3(8, 64), dim3(256), 0, stream, X, Y, hp, out);
}

// Round 4
// 17.365 us; speedup vs baseline: 1.5180x; 1.1926x over previous
//
#include <hip/hip_runtime.h>

#define NN 1024
#define DD 128

typedef float f32x4 __attribute__((ext_vector_type(4)));
typedef _Float16 f16x4 __attribute__((ext_vector_type(4)));
typedef _Float16 f16x8 __attribute__((ext_vector_type(8)));

__device__ __forceinline__ f16x8 cvt8(f32x4 a, f32x4 b) {
  f16x8 r;
  r[0] = (_Float16)a.x; r[1] = (_Float16)a.y; r[2] = (_Float16)a.z; r[3] = (_Float16)a.w;
  r[4] = (_Float16)b.x; r[5] = (_Float16)b.y; r[6] = (_Float16)b.z; r[7] = (_Float16)b.w;
  return r;
}

// ws layout (f32 units):
//   [0 .. 8192)            S_part[js][i]   (8 x 1024)
//   [8192 .. 8192+1048576) part[js][i][d]  (8 x 1024 x 128) unscaled K'@Y GEMM values
#define WS_PART 8192

// Grid (8 js, 64 ib), 256 threads = 4 waves. Block tile 16 i x 128 j.
// Swapped QK^T (lane=col=i, regs=row=j), per-row dynamic-scaled f16 K' for the
// second MFMA. No global atomics: partials go to private ws slabs.
__global__ __launch_bounds__(256, 2) void gk_main(const float* __restrict__ X,
                                                  const float* __restrict__ Y,
                                                  const int* __restrict__ hp,
                                                  float* __restrict__ out,
                                                  float* __restrict__ ws) {
  __shared__ __align__(16) _Float16 Ks[16][136];   // K' f16 scaled
  __shared__ float yys[128];
  __shared__ unsigned msc[16];
  __shared__ float Sred[16];

  const int tid  = threadIdx.x;
  const int js   = blockIdx.x;          // 0..7   (j block of 128)
  const int ib   = blockIdx.y;          // 0..63  (i block of 16)
  const int lane = tid & 63;
  const int w    = tid >> 6;            // wave 0..3
  const int g    = lane >> 4;           // k-group 0..3
  const int li   = lane & 15;

  const float fh = (float)hp[0];
  const float inv_h2 = 1.0f / (fh * fh);

  if (tid < 16) { msc[tid] = 0u; Sred[tid] = 0.0f; }

  // ---- issue ALL independent global loads up front ----
  // X fragments (B-operand of QK^T) + |x|^2 partial
  const float* Xr = X + (size_t)(ib * 16 + li) * DD;
  f32x4 xa[4][2];
  #pragma unroll
  for (int kt = 0; kt < 4; ++kt) {
    int d0 = kt * 32 + g * 8;
    xa[kt][0] = *(const f32x4*)(Xr + d0);
    xa[kt][1] = *(const f32x4*)(Xr + d0 + 4);
  }
  // phase-D B-operand prefetch: Y columns, lane=d (64B-coalesced per 16-lane group)
  const int dA = w * 32 + li;
  const int dB = dA + 16;
  float bpre0[4][8], bpre1[4][8];
  #pragma unroll
  for (int kt = 0; kt < 4; ++kt) {
    const float* Yb = Y + (size_t)(js * 128 + kt * 32 + g * 8) * DD;
    #pragma unroll
    for (int e = 0; e < 8; ++e) {
      bpre0[kt][e] = Yb[e * DD + dA];
      bpre1[kt][e] = Yb[e * DD + dB];
    }
  }

  float xx = 0.f;
  #pragma unroll
  for (int kt = 0; kt < 4; ++kt)
    #pragma unroll
    for (int c = 0; c < 4; ++c)
      xx += xa[kt][0][c] * xa[kt][0][c] + xa[kt][1][c] * xa[kt][1][c];
  xx += __shfl_xor(xx, 16); xx += __shfl_xor(xx, 32);

  // ---- Phase A: QK^T from global f32 Y rows (A-operand), norms in-register ----
  const float* Yr0 = Y + (size_t)(js * 128 + w * 32 + li) * DD;
  const float* Yr1 = Yr0 + 16 * DD;
  f32x4 acc0 = {0.f, 0.f, 0.f, 0.f}, acc1 = {0.f, 0.f, 0.f, 0.f};
  float yy0 = 0.f, yy1 = 0.f;
  #pragma unroll
  for (int kt = 0; kt < 4; ++kt) {
    int d0 = kt * 32 + g * 8;
    f32x4 a0 = *(const f32x4*)(Yr0 + d0), b0 = *(const f32x4*)(Yr0 + d0 + 4);
    f32x4 a1 = *(const f32x4*)(Yr1 + d0), b1 = *(const f32x4*)(Yr1 + d0 + 4);
    #pragma unroll
    for (int c = 0; c < 4; ++c) {
      yy0 += a0[c] * a0[c] + b0[c] * b0[c];
      yy1 += a1[c] * a1[c] + b1[c] * b1[c];
    }
    f16x8 bf = cvt8(xa[kt][0], xa[kt][1]);
    acc0 = __builtin_amdgcn_mfma_f32_16x16x32_f16(cvt8(a0, b0), bf, acc0, 0, 0, 0);
    acc1 = __builtin_amdgcn_mfma_f32_16x16x32_f16(cvt8(a1, b1), bf, acc1, 0, 0, 0);
  }
  yy0 += __shfl_xor(yy0, 16); yy0 += __shfl_xor(yy0, 32);
  yy1 += __shfl_xor(yy1, 16); yy1 += __shfl_xor(yy1, 32);
  if (lane < 16) { yys[w * 32 + lane] = yy0; yys[w * 32 + 16 + lane] = yy1; }
  __syncthreads();   // b1: yys ready, msc/Sred init visible

  // ---- exp: K = exp(inv_h2*(xy - 0.5(xx+yy))) clamped <= 1; stats in-reg ----
  float K[8];
  float m = 0.f, sp = 0.f;
  #pragma unroll
  for (int t = 0; t < 2; ++t) {
    f32x4 a = t ? acc1 : acc0;
    #pragma unroll
    for (int r = 0; r < 4; ++r) {
      int jl = w * 32 + t * 16 + 4 * g + r;            // C/D row map (16x16)
      float e = fminf((a[r] - 0.5f * (xx + yys[jl])) * inv_h2, 0.0f);
      float kv = exp2f(e * 1.44269504088896341f);
      K[t * 4 + r] = kv; m = fmaxf(m, kv); sp += kv;
    }
  }
  // direct K store: per instr, 4 g-lanes x 16 li-rows cover 16 full 64B lines
  {
    float* kb = out + (size_t)(ib * 16 + li) * NN + js * 128 + w * 32 + 4 * g;
    f32x4 k0 = { K[0], K[1], K[2], K[3] };
    f32x4 k1 = { K[4], K[5], K[6], K[7] };
    *(f32x4*)kb = k0;
    *(f32x4*)(kb + 16) = k1;
  }
  m = fmaxf(m, __shfl_xor(m, 16)); m = fmaxf(m, __shfl_xor(m, 32));
  sp += __shfl_xor(sp, 16);        sp += __shfl_xor(sp, 32);
  if (lane < 16) {
    atomicMax(&msc[li], __float_as_uint(m));
    atomicAdd(&Sred[li], sp);
  }
  __syncthreads();   // b2: msc, Sred complete

  // ---- scaled K' (f16) for phase D ----
  {
    unsigned ue = (msc[li] >> 23) & 0xffu;
    unsigned se = 266u - ue; if (se > 254u) se = 254u;  // K'max in [2^12,2^13)
    float scale = __uint_as_float(se << 23);
    #pragma unroll
    for (int t = 0; t < 2; ++t) {
      f16x4 q;
      #pragma unroll
      for (int r = 0; r < 4; ++r) q[r] = (_Float16)(K[t * 4 + r] * scale);
      *(f16x4*)&Ks[li][w * 32 + t * 16 + 4 * g] = q;
    }
  }
  __syncthreads();   // b3: Ks ready

  // ---- Phase D: K' @ Y, B-operand from prefetched registers ----
  f32x4 c0 = {0.f, 0.f, 0.f, 0.f}, c1 = {0.f, 0.f, 0.f, 0.f};
  #pragma unroll
  for (int kt = 0; kt < 4; ++kt) {
    f16x8 af = *(const f16x8*)&Ks[li][kt * 32 + g * 8];
    f16x8 b0, b1;
    #pragma unroll
    for (int e = 0; e < 8; ++e) {
      b0[e] = (_Float16)bpre0[kt][e];
      b1[e] = (_Float16)bpre1[kt][e];
    }
    c0 = __builtin_amdgcn_mfma_f32_16x16x32_f16(af, b0, c0, 0, 0, 0);
    c1 = __builtin_amdgcn_mfma_f32_16x16x32_f16(af, b1, c1, 0, 0, 0);
  }

  // ---- epilogue: unscale, store private partial slab (no atomics) ----
  float* pb = ws + WS_PART + (size_t)js * (NN * DD) + (size_t)(ib * 16) * DD;
  #pragma unroll
  for (int r = 0; r < 4; ++r) {
    int il = 4 * g + r;
    unsigned ue2 = (msc[il] >> 23) & 0xffu;
    unsigned se2 = 266u - ue2; if (se2 > 254u) se2 = 254u;
    float invs = __uint_as_float((254u - se2) << 23);   // 1/scale for row il
    pb[il * DD + dA] = c0[r] * invs;
    pb[il * DD + dB] = c1[r] * invs;
  }
  if (tid < 16) ws[js * NN + ib * 16 + tid] = Sred[tid];
}

// Reduce the 8 js-slabs: dK[i][d] = inv_h2 * (sum_js part - (sum_js S) * X[i][d])
__global__ __launch_bounds__(256) void dk_reduce(const float* __restrict__ X,
                                                 const int* __restrict__ hp,
                                                 const float* __restrict__ ws,
                                                 float* __restrict__ out) {
  const int unit = blockIdx.x * 256 + threadIdx.x;   // 0..32767 (f32x4 units)
  const int i  = unit >> 5;
  const int d0 = (unit & 31) * 4;
  const float fh = (float)hp[0];
  const float inv_h2 = 1.0f / (fh * fh);

  f32x4 acc = {0.f, 0.f, 0.f, 0.f};
  float s = 0.f;
  #pragma unroll
  for (int js = 0; js < 8; ++js) {
    f32x4 p = *(const f32x4*)(ws + WS_PART + (size_t)js * (NN * DD) + (size_t)i * DD + d0);
    acc.x += p.x; acc.y += p.y; acc.z += p.z; acc.w += p.w;
    s += ws[js * NN + i];
  }
  f32x4 xv = *(const f32x4*)(X + (size_t)i * DD + d0);
  f32x4 r;
  r.x = (acc.x - s * xv.x) * inv_h2;
  r.y = (acc.y - s * xv.y) * inv_h2;
  r.z = (acc.z - s * xv.z) * inv_h2;
  r.w = (acc.w - s * xv.w) * inv_h2;
  *(f32x4*)(out + (size_t)NN * NN + (size_t)i * DD + d0) = r;
}

extern "C" void kernel_launch(void* const* d_in, const int* in_sizes, int n_in,
                              void* d_out, int out_size, void* d_ws, size_t ws_size,
                              hipStream_t stream) {
  const float* X  = (const float*)d_in[0];
  const float* Y  = (const float*)d_in[1];
  const int*   hp = (const int*)d_in[2];
  float* out = (float*)d_out;
  float* ws  = (float*)d_ws;    // needs (8192 + 1048576) f32 ≈ 4.2 MB

  hipLaunchKernelGGL(gk_main, dim3(8, 64), dim3(256), 0, stream, X, Y, hp, out, ws);
  hipLaunchKernelGGL(dk_reduce, dim3(128), dim3(256), 0, stream, X, hp, ws, out);
}